// Round 3
// baseline (1118.969 us; speedup 1.0000x reference)
//
#include <hip/hip_runtime.h>
#include <hip/hip_bf16.h>
#include <stdint.h>

#define V_SZ 100000
#define D_SZ 512
#define B_SZ 1024
#define C_SZ 20
#define NEG 64
#define NB 2048
#define CAP 512

// ---- Cephes f32 log matching XLA-CPU GenerateVF32Log (FMA polynomial chain,
// separate mul/add tail). fp contract(off) so hipcc can't re-fuse differently.
__device__ __forceinline__ float xla_logf(float xin) {
#pragma clang fp contract(off)
  float x = fmaxf(xin, 1.17549435e-38f);            // clamp to min normal
  uint32_t bits = __float_as_uint(x);
  float e = (float)((int)(bits >> 23) - 127) + 1.0f;
  float m = __uint_as_float((bits & 0x807fffffu) | 0x3f000000u);  // [0.5,1)
  bool lt = m < 0.707106781186547524f;
  float tmp = lt ? m : 0.0f;
  m = m - 1.0f;
  e = e - (lt ? 1.0f : 0.0f);
  m = m + tmp;
  float z = m * m;
  float y = 7.0376836292E-2f;
  y = fmaf(y, m, -1.1514610310E-1f);
  y = fmaf(y, m, 1.1676998740E-1f);
  y = fmaf(y, m, -1.2420140846E-1f);
  y = fmaf(y, m, 1.4249322787E-1f);
  y = fmaf(y, m, -1.6668057665E-1f);
  y = fmaf(y, m, 2.0000714765E-1f);
  y = fmaf(y, m, -2.4999993993E-1f);
  y = fmaf(y, m, 3.3333331174E-1f);
  y = y * m;
  y = y * z;
  y = y + e * (-2.12194440e-4f);
  y = y - z * 0.5f;
  x = m + y;
  x = x + e * 0.693359375f;
  return x;
}

// ---- Threefry-2x32, 20 rounds, key = jax.random.key(42) -> (0, 42). ----
__device__ __forceinline__ void threefry2x32(uint32_t x0, uint32_t x1,
                                             uint32_t& o0, uint32_t& o1) {
  const uint32_t ks1 = 42u, ks2 = 0x1BD11BF0u;  // 0 ^ 42 ^ 0x1BD11BDA
#define TFR(r) { x0 += x1; x1 = (x1 << (r)) | (x1 >> (32 - (r))); x1 ^= x0; }
  x0 += 0u; x1 += ks1;
  TFR(13) TFR(15) TFR(26) TFR(6)
  x0 += ks1; x1 += ks2 + 1u;
  TFR(17) TFR(29) TFR(16) TFR(24)
  x0 += ks2; x1 += 0u + 2u;
  TFR(13) TFR(15) TFR(26) TFR(6)
  x0 += 0u; x1 += ks1 + 3u;
  TFR(17) TFR(29) TFR(16) TFR(24)
  x0 += ks1; x1 += ks2 + 4u;
  TFR(13) TFR(15) TFR(26) TFR(6)
  x0 += ks2; x1 += 0u + 5u;
#undef TFR
  o0 = x0; o1 = x1;
}

// PARTITIONABLE threefry (modern JAX default): element i uses 64-bit counter i
// -> block input (hi,lo) = (i>>32, i&0xffffffff) = (0, i) here; 32-bit draw is
// out0 ^ out1.
__device__ __forceinline__ uint32_t tf_bits_partitionable(uint32_t i) {
  uint32_t o0, o1;
  threefry2x32(0u, i, o0, o1);
  return o0 ^ o1;
}

// u = max(tiny, f*(1-tiny)+tiny) with f from 23 mantissa bits; algebraically
// exact simplification: u = (f > 0) ? f : FLT_MIN.  Then g = -log(-log(u)).
__device__ __forceinline__ float gumbel_from_bits(uint32_t bits) {
#pragma clang fp contract(off)
  float f = __uint_as_float((bits >> 9) | 0x3f800000u) - 1.0f;
  float u = (bits >> 9) ? f : 1.17549435e-38f;
  return -xla_logf(-xla_logf(u));
}

// Single helper used by BOTH passes so rounding is identical in each.
__device__ __forceinline__ float score_one(uint32_t i, float lpv) {
#pragma clang fp contract(off)
  return lpv + gumbel_from_bits(tf_bits_partitionable(i));
}

__global__ __launch_bounds__(256) void compute_lp(const float* __restrict__ sp,
                                                  float* __restrict__ lp) {
  int v = blockIdx.x * 256 + threadIdx.x;
  if (v < V_SZ) lp[v] = xla_logf(sp[v]);
}

// One block per batch row. Histogram -> cut bin -> collect -> exact rank.
__global__ __launch_bounds__(256) void select_negs(const float* __restrict__ lp,
                                                   int* __restrict__ negidx) {
  __shared__ uint32_t hist[NB];
  __shared__ float cs[CAP];
  __shared__ int   ci[CAP];
  __shared__ int   cnt;
  __shared__ int   cut;

  const int b = blockIdx.x;                       // 0..1023
  const uint32_t base = (uint32_t)b * (uint32_t)V_SZ;   // < 2^32
  const float LO = -28.0f, INVW = 51.2f;          // 2048 bins over [-28,12)

  for (int i = threadIdx.x; i < NB; i += 256) hist[i] = 0u;
  if (threadIdx.x == 0) cnt = 0;
  __syncthreads();

  // Pass 1: histogram scores.
  for (int v = threadIdx.x; v < V_SZ; v += 256) {
    float s = score_one(base + (uint32_t)v, lp[v]);
    int bin = min(NB - 1, max(0, (int)((s - LO) * INVW)));
    atomicAdd(&hist[bin], 1u);
  }
  __syncthreads();

  // Suffix-scan from the top until cumulative >= 64.
  if (threadIdx.x == 0) {
    uint32_t acc = 0; int c = NB - 1;
    for (; c > 0; --c) { acc += hist[c]; if (acc >= (uint32_t)NEG) break; }
    cut = c;
  }
  __syncthreads();
  const int cutb = cut;

  // Pass 2: recompute and collect candidates (bin >= cut).
  for (int v = threadIdx.x; v < V_SZ; v += 256) {
    float s = score_one(base + (uint32_t)v, lp[v]);
    int bin = min(NB - 1, max(0, (int)((s - LO) * INVW)));
    if (bin >= cutb) {
      int k = atomicAdd(&cnt, 1);
      if (k < CAP) { cs[k] = s; ci[k] = v; }
    }
  }
  __syncthreads();

  // Exact O(n^2) rank; ties -> lower index first (lax.top_k stability).
  int n = min(cnt, CAP);
  for (int i = threadIdx.x; i < n; i += 256) {
    float si = cs[i]; int vi = ci[i];
    int rank = 0;
    for (int j = 0; j < n; ++j) {
      float sj = cs[j];
      rank += (sj > si) || (sj == si && ci[j] < vi);
    }
    if (rank < NEG) negidx[b * NEG + rank] = vi;
  }
}

// One block per batch row: center row in LDS, one wave per dot.
__global__ __launch_bounds__(256) void dots(const int* __restrict__ center_ids,
                                            const int* __restrict__ context_ids,
                                            const float* __restrict__ Wcen,
                                            const float* __restrict__ Wctx,
                                            const int* __restrict__ negidx,
                                            float* __restrict__ out) {
  __shared__ float cen[D_SZ];
  const int b = blockIdx.x;
  const int cid = center_ids[b];
  const float4* crow = (const float4*)(Wcen + (size_t)cid * D_SZ);
  for (int i = threadIdx.x; i < D_SZ / 4; i += 256) ((float4*)cen)[i] = crow[i];
  __syncthreads();

  const int wave = threadIdx.x >> 6, lane = threadIdx.x & 63;
  for (int item = wave; item < C_SZ + NEG; item += 4) {
    const float* row;
    if (item < C_SZ) row = Wcen + (size_t)context_ids[b * C_SZ + item] * D_SZ;
    else             row = Wctx + (size_t)negidx[b * NEG + (item - C_SZ)] * D_SZ;
    const float4* r4 = (const float4*)row;
    float4 a0 = r4[lane * 2], a1 = r4[lane * 2 + 1];
    float4 c0 = ((const float4*)cen)[lane * 2];
    float4 c1 = ((const float4*)cen)[lane * 2 + 1];
    float p = a0.x * c0.x + a0.y * c0.y + a0.z * c0.z + a0.w * c0.w +
              a1.x * c1.x + a1.y * c1.y + a1.z * c1.z + a1.w * c1.w;
    for (int off = 32; off; off >>= 1) p += __shfl_xor(p, off, 64);
    if (lane == 0) {
      if (item < C_SZ) out[b * C_SZ + item] = p;
      else out[B_SZ * C_SZ + b * NEG + (item - C_SZ)] = p;
    }
  }
}

extern "C" void kernel_launch(void* const* d_in, const int* in_sizes, int n_in,
                              void* d_out, int out_size, void* d_ws, size_t ws_size,
                              hipStream_t stream) {
  (void)in_sizes; (void)n_in; (void)out_size; (void)ws_size;
  const int*   center_ids  = (const int*)d_in[0];
  const int*   context_ids = (const int*)d_in[1];
  const float* Wcen        = (const float*)d_in[2];
  const float* Wctx        = (const float*)d_in[3];
  const float* sp          = (const float*)d_in[4];
  // d_in[5] = neg_sample (=64), compile-time constant here.

  float* lp     = (float*)d_ws;                       // V floats (400 KB)
  int*   negidx = (int*)((char*)d_ws + 512 * 1024);   // B*64 ints (256 KB)

  compute_lp <<<(V_SZ + 255) / 256, 256, 0, stream>>>(sp, lp);
  select_negs<<<B_SZ,               256, 0, stream>>>(lp, negidx);
  dots       <<<B_SZ,               256, 0, stream>>>(center_ids, context_ids,
                                                      Wcen, Wctx, negidx,
                                                      (float*)d_out);
}